// Round 7
// baseline (365.646 us; speedup 1.0000x reference)
//
#include <hip/hip_runtime.h>
#include <cstdint>

// ---------- types ----------
typedef __bf16 bf16x8 __attribute__((ext_vector_type(8)));
typedef float  floatx4 __attribute__((ext_vector_type(4)));

__device__ __forceinline__ unsigned short f2bf(float x) {
  union { float f; uint32_t u; } v; v.f = x;
  uint32_t r = (v.u + 0x7FFFu + ((v.u >> 16) & 1u)) >> 16;
  return (unsigned short)r;
}
__device__ __forceinline__ float bflo(uint32_t u) {
  union { uint32_t u; float f; } v; v.u = u << 16; return v.f;
}
__device__ __forceinline__ float bfhi(uint32_t u) {
  union { uint32_t u; float f; } v; v.u = u & 0xffff0000u; return v.f;
}

// async global->LDS, 16B per lane. LDS dest must be wave-uniform base; HW adds lane*16.
__device__ __forceinline__ void async_copy16(const void* g, void* l) {
  __builtin_amdgcn_global_load_lds(
      (const __attribute__((address_space(1))) uint32_t*)g,
      (__attribute__((address_space(3))) uint32_t*)l, 16, 0, 0);
}

// ---------- bf16 GEMM: C[M,N] = A[M,K] @ Bt[N,K]^T + bias ----------
// 128x128 tile, BK=32, 4 waves 2x2, 4x4 mfma_f32_16x16x32_bf16 per wave.
// PIPELINED K-loop: double-buffered LDS; next tile's global_load_lds issued BEFORE
// s_waitcnt vmcnt(4). Raw s_barrier so the compiler can't insert a vmcnt(0) drain.
// XOR-swizzled LDS (2-way = free). XCD + 8x8-square block swizzle for L2 locality.
template<int OUT_BF16, int RELU>
__global__ __launch_bounds__(256, 2)
void gemm_bt_kernel(const unsigned short* __restrict__ A,
                    const unsigned short* __restrict__ Bt,
                    void* __restrict__ C, const float* __restrict__ bias,
                    int M, int N, int K, int Kper) {
  __shared__ __align__(16) unsigned short l0A[128 * 32];
  __shared__ __align__(16) unsigned short l0B[128 * 32];
  __shared__ __align__(16) unsigned short l1A[128 * 32];
  __shared__ __align__(16) unsigned short l1B[128 * 32];
  const int tid  = threadIdx.x;
  const int wave = tid >> 6;
  const int lane = tid & 63;

  // XCD + 8x8-square block swizzle (bijective remap of the x,y block grid)
  const int gx = gridDim.x, gy = gridDim.y;
  int flat = blockIdx.y * gx + blockIdx.x;
  const int per = (gx * gy) >> 3;
  flat = (flat & 7) * per + (flat >> 3);
  const int sq = flat >> 6, inner = flat & 63;
  const int sqm = gy >> 3;
  const int m0 = ((sq % sqm) * 8 + (inner & 7)) * 128;
  const int n0 = ((sq / sqm) * 8 + (inner >> 3)) * 128;

  const int kz = blockIdx.z;
  const int wm = (wave >> 1) * 64;
  const int wn = (wave & 1) * 64;
  const int sa_row = lane >> 2;
  const int sa_k   = ((lane & 3) ^ ((lane >> 3) & 3)) * 8;
  const int fr = lane & 15;
  const int fq = lane >> 4;
  const int sw = (fr >> 1) & 3;

  const int r0 = (wave * 2 + 0) * 16 + sa_row;
  const int r1 = (wave * 2 + 1) * 16 + sa_row;
  const unsigned short* A0 = A  + (size_t)(m0 + r0) * K + kz * Kper + sa_k;
  const unsigned short* A1 = A  + (size_t)(m0 + r1) * K + kz * Kper + sa_k;
  const unsigned short* B0 = Bt + (size_t)(n0 + r0) * K + kz * Kper + sa_k;
  const unsigned short* B1 = Bt + (size_t)(n0 + r1) * K + kz * Kper + sa_k;

  floatx4 acc[4][4];
  #pragma unroll
  for (int i = 0; i < 4; ++i)
    #pragma unroll
    for (int j = 0; j < 4; ++j)
      acc[i][j] = (floatx4){0.f, 0.f, 0.f, 0.f};

  const int c0 = (wave * 2 + 0) * 512;
  const int c1 = (wave * 2 + 1) * 512;

#define PREFETCH(kt, LA, LB)                                   \
  do {                                                         \
    const int koff = (kt) << 5;                                \
    async_copy16(A0 + koff, &(LA)[c0]);                        \
    async_copy16(A1 + koff, &(LA)[c1]);                        \
    async_copy16(B0 + koff, &(LB)[c0]);                        \
    async_copy16(B1 + koff, &(LB)[c1]);                        \
  } while (0)

#define COMPUTE(LA, LB)                                                        \
  do {                                                                         \
    bf16x8 af[4], bf[4];                                                       \
    _Pragma("unroll")                                                          \
    for (int t = 0; t < 4; ++t) {                                              \
      af[t] = *(const bf16x8*)&(LA)[(wm + t * 16 + fr) * 32 + (fq ^ sw) * 8];  \
      bf[t] = *(const bf16x8*)&(LB)[(wn + t * 16 + fr) * 32 + (fq ^ sw) * 8];  \
    }                                                                          \
    _Pragma("unroll")                                                          \
    for (int mt = 0; mt < 4; ++mt)                                             \
      _Pragma("unroll")                                                        \
      for (int nt = 0; nt < 4; ++nt)                                           \
        acc[mt][nt] = __builtin_amdgcn_mfma_f32_16x16x32_bf16(af[mt], bf[nt],  \
                                                              acc[mt][nt], 0, 0, 0); \
  } while (0)

  const int kIters = Kper >> 5;   // always even (>=8) for our shapes
  PREFETCH(0, l0A, l0B);
  for (int kt = 0; kt < kIters; kt += 2) {
    PREFETCH(kt + 1, l1A, l1B);
    asm volatile("s_waitcnt vmcnt(4)" ::: "memory");
    asm volatile("s_barrier" ::: "memory");
    COMPUTE(l0A, l0B);
    asm volatile("s_barrier" ::: "memory");
    if (kt + 2 < kIters) {
      PREFETCH(kt + 2, l0A, l0B);
      asm volatile("s_waitcnt vmcnt(4)" ::: "memory");
    } else {
      asm volatile("s_waitcnt vmcnt(0)" ::: "memory");
    }
    asm volatile("s_barrier" ::: "memory");
    COMPUTE(l1A, l1B);
    asm volatile("s_barrier" ::: "memory");
  }
#undef PREFETCH
#undef COMPUTE

  const float* bp = (kz == 0) ? bias : nullptr;
  char* Cz = (char*)C + (size_t)kz * M * N * (OUT_BF16 ? 2 : 4);
  #pragma unroll
  for (int mt = 0; mt < 4; ++mt) {
    #pragma unroll
    for (int nt = 0; nt < 4; ++nt) {
      const int gn = n0 + wn + nt * 16 + fr;
      const float bv = bp ? bp[gn] : 0.f;
      #pragma unroll
      for (int r = 0; r < 4; ++r) {
        const int gm = m0 + wm + mt * 16 + fq * 4 + r;
        float v = acc[mt][nt][r] + bv;
        if (RELU) v = fmaxf(v, 0.f);
        if (OUT_BF16) ((unsigned short*)Cz)[(size_t)gm * N + gn] = f2bf(v);
        else          ((float*)Cz)[(size_t)gm * N + gn] = v;
      }
    }
  }
}

// ---------- repack V: QKVb bf16 [4096,3072] -> Vt [bh][d][s] ----------
// Keys PERMUTED within each 64-tile: position c holds key (c&3)*16 + (c>>2),
// matching the packed-P column layout in flash_attn (dot over k is perm-invariant).
__global__ __launch_bounds__(256)
void repack_v_kernel(const unsigned short* __restrict__ X,
                     unsigned short* __restrict__ Vt) {
  const int bid = blockIdx.x;                 // 1024 = b(2) x h(16) x stile(32)
  const int st = bid & 31, h = (bid >> 5) & 15, b = bid >> 9;
  const int bh = b * 16 + h;
  const int s0 = st * 64;
  const int t = threadIdx.x;
  const int sl = t >> 2;
  const int c  = (t & 3) * 16;
  __shared__ __align__(16) unsigned short vt[64][72];
  {
    const uint4* srcV = (const uint4*)(X + (size_t)(b * 2048 + s0 + sl) * 3072 + 2048 + h * 64 + c);
    uint4* dstL = (uint4*)&vt[sl][c];
    dstL[0] = srcV[0]; dstL[1] = srcV[1];
  }
  __syncthreads();
  const int d = t >> 2, cc = (t & 3) * 16;
  unsigned short tmp[16];
  #pragma unroll
  for (int j = 0; j < 16; ++j) {
    const int chat = cc + j;
    const int key = (chat & 3) * 16 + (chat >> 2);   // permutation
    tmp[j] = vt[key][d];
  }
  uint4* dstV = (uint4*)(Vt + ((size_t)bh * 64 + d) * 2048 + s0 + cc);
  dstV[0] = *(uint4*)&tmp[0];
  dstV[1] = *(uint4*)&tmp[8];
}

// ---------- flash attention (MFMA, max-free softmax, key-split x2, PIPELINED) ----------
// Block: (ksp, b, h, 128-query tile); 4 waves x 32 queries; 16 key-tiles of 64 per part.
// Double-buffered lK/lV with raw s_barrier + vmcnt(4) prefetch pipeline (GEMM-style).
// Writes UNNORMALIZED bf16 Opart [ksp][bh*2048+q][64] and fp32 Lpart [ksp][bh*2048+q].
__global__ __launch_bounds__(256, 3)
void flash_attn_kernel(const unsigned short* __restrict__ QKVb,
                       const unsigned short* __restrict__ Vt,
                       unsigned short* __restrict__ Opart, float* __restrict__ Lpart) {
  const int bid = blockIdx.x;               // 1024 = ksp(2) x b(2) x h(16) x qtile(16)
  const int qt = bid & 15, h = (bid >> 4) & 15, b = (bid >> 8) & 1, ksp = bid >> 9;
  const int bh = b * 16 + h;
  const int wave = threadIdx.x >> 6, lane = threadIdx.x & 63;
  const int fr = lane & 15, fq = lane >> 4;

  __shared__ __align__(16) unsigned short lK0[64 * 64];     // [key][d] swizzled
  __shared__ __align__(16) unsigned short lV0[64 * 64];     // [d][key~perm] swizzled
  __shared__ __align__(16) unsigned short lK1[64 * 64];
  __shared__ __align__(16) unsigned short lV1[64 * 64];
  __shared__ __align__(16) unsigned short lP[4][32 * 72];   // per-wave [q][key~perm]

  const int q_base = qt * 128 + wave * 32;
  // Q fragments direct from QKVb (faithful gather: row = h*128 + s2/16, col = (s2%16)*64 + d)
  bf16x8 aq[2][2];
  #pragma unroll
  for (int g = 0; g < 2; ++g) {
    const int s2 = q_base + g * 16 + fr;
    const unsigned short* qp = QKVb + (size_t)(b * 2048 + h * 128 + (s2 >> 4)) * 3072
                             + (s2 & 15) * 64 + fq * 8;
    aq[g][0] = *(const bf16x8*)qp;
    aq[g][1] = *(const bf16x8*)(qp + 32);
  }
  floatx4 o_acc[2][4];
  #pragma unroll
  for (int g = 0; g < 2; ++g)
    #pragma unroll
    for (int nt = 0; nt < 4; ++nt) o_acc[g][nt] = (floatx4){0.f, 0.f, 0.f, 0.f};
  float lrow[2][4];
  #pragma unroll
  for (int g = 0; g < 2; ++g)
    #pragma unroll
    for (int r = 0; r < 4; ++r) lrow[g][r] = 0.f;

  const unsigned short* Kg = QKVb + 1024 + h * 64;
  const unsigned short* Vg = Vt + (size_t)bh * 64 * 2048;

  const int srow = lane >> 3;
  const int scol = ((lane & 7) ^ (lane >> 3)) * 8;
  const int sw = fr & 7;
  const int ch0 = wave * 2, ch1 = wave * 2 + 1;
  const int krow0 = ch0 * 8 + srow, krow1 = ch1 * 8 + srow;

  auto pref = [&](int kt, unsigned short* LK, unsigned short* LV) {
    async_copy16(Kg + (size_t)(b * 2048 + kt * 64 + krow0) * 3072 + scol, (char*)LK + ch0 * 1024);
    async_copy16(Vg + (size_t)krow0 * 2048 + kt * 64 + scol,              (char*)LV + ch0 * 1024);
    async_copy16(Kg + (size_t)(b * 2048 + kt * 64 + krow1) * 3072 + scol, (char*)LK + ch1 * 1024);
    async_copy16(Vg + (size_t)krow1 * 2048 + kt * 64 + scol,              (char*)LV + ch1 * 1024);
  };

  auto compute_tile = [&](const unsigned short* LK, const unsigned short* LV) {
    // S = Q @ K^T
    floatx4 s_acc[2][4];
    #pragma unroll
    for (int nt = 0; nt < 4; ++nt) {
      const int row = (nt * 16 + fr) * 64;
      bf16x8 bk0 = *(const bf16x8*)&LK[row + ((0 + fq) ^ sw) * 8];
      bf16x8 bk1 = *(const bf16x8*)&LK[row + ((4 + fq) ^ sw) * 8];
      #pragma unroll
      for (int g = 0; g < 2; ++g) {
        floatx4 acc = (floatx4){0.f, 0.f, 0.f, 0.f};
        acc = __builtin_amdgcn_mfma_f32_16x16x32_bf16(aq[g][0], bk0, acc, 0, 0, 0);
        acc = __builtin_amdgcn_mfma_f32_16x16x32_bf16(aq[g][1], bk1, acc, 0, 0, 0);
        s_acc[g][nt] = acc;
      }
    }
    // p = exp2(s * 0.125*log2e); packed b64 write: key nt*16+fr stored at column fr*4+nt
    #pragma unroll
    for (int g = 0; g < 2; ++g) {
      #pragma unroll
      for (int r = 0; r < 4; ++r) {
        const float p0 = __builtin_amdgcn_exp2f(s_acc[g][0][r] * 0.18033688f);
        const float p1 = __builtin_amdgcn_exp2f(s_acc[g][1][r] * 0.18033688f);
        const float p2 = __builtin_amdgcn_exp2f(s_acc[g][2][r] * 0.18033688f);
        const float p3 = __builtin_amdgcn_exp2f(s_acc[g][3][r] * 0.18033688f);
        lrow[g][r] += (p0 + p1) + (p2 + p3);
        union { float f; uint32_t u; } c0, c1, c2, c3;
        c0.f = p0; c1.f = p1; c2.f = p2; c3.f = p3;
        uint2 pk;
        pk.x = (c1.u & 0xffff0000u) | (c0.u >> 16);
        pk.y = (c3.u & 0xffff0000u) | (c2.u >> 16);
        *(uint2*)&lP[wave][(g * 16 + fq * 4 + r) * 72 + fr * 4] = pk;
      }
    }
    // O += P @ V  (both k-dims in permuted key order; lP wave-private -> no barrier)
    #pragma unroll
    for (int g = 0; g < 2; ++g) {
      #pragma unroll
      for (int kk = 0; kk < 2; ++kk) {
        bf16x8 ap = *(const bf16x8*)&lP[wave][(g * 16 + fr) * 72 + kk * 32 + fq * 8];
        #pragma unroll
        for (int nt = 0; nt < 4; ++nt) {
          bf16x8 bv = *(const bf16x8*)&LV[(nt * 16 + fr) * 64 + ((kk * 4 + fq) ^ sw) * 8];
          o_acc[g][nt] = __builtin_amdgcn_mfma_f32_16x16x32_bf16(ap, bv, o_acc[g][nt], 0, 0, 0);
        }
      }
    }
  };

  const int kt0 = ksp * 16;
  pref(kt0, lK0, lV0);
  for (int kt = kt0; kt < kt0 + 16; kt += 2) {
    pref(kt + 1, lK1, lV1);
    asm volatile("s_waitcnt vmcnt(4)" ::: "memory");
    asm volatile("s_barrier" ::: "memory");
    compute_tile(lK0, lV0);
    asm volatile("s_barrier" ::: "memory");
    if (kt + 2 < kt0 + 16) {
      pref(kt + 2, lK0, lV0);
      asm volatile("s_waitcnt vmcnt(4)" ::: "memory");
    } else {
      asm volatile("s_waitcnt vmcnt(0)" ::: "memory");
    }
    asm volatile("s_barrier" ::: "memory");
    compute_tile(lK1, lV1);
    asm volatile("s_barrier" ::: "memory");
  }

  // epilogue: unnormalized bf16 partials + fp32 row sums
  const size_t rbase = (size_t)ksp * 65536 + (size_t)bh * 2048 + q_base;
  #pragma unroll
  for (int g = 0; g < 2; ++g) {
    #pragma unroll
    for (int r = 0; r < 4; ++r) {
      float l = lrow[g][r];
      #pragma unroll
      for (int off = 1; off < 16; off <<= 1) l += __shfl_xor(l, off);
      if (fr == 0) Lpart[rbase + g * 16 + fq * 4 + r] = l;
    }
    #pragma unroll
    for (int nt = 0; nt < 4; ++nt)
      #pragma unroll
      for (int r = 0; r < 4; ++r)
        Opart[(rbase + g * 16 + fq * 4 + r) * 64 + nt * 16 + fr] = f2bf(o_acc[g][nt][r]);
  }
}

// ---------- combine the two key-split halves: Ob = (O0+O1)/(l0+l1), bf16 ----------
__global__ __launch_bounds__(256)
void attn_combine_kernel(const unsigned short* __restrict__ Opart,
                         const float* __restrict__ Lpart,
                         unsigned short* __restrict__ O) {
  const int i = blockIdx.x * 256 + threadIdx.x;   // 512K threads, 8 d-elems each
  const int row = i >> 3;                         // bh*2048 + q
  const int d8 = (i & 7) * 8;
  const uint4 a = *(const uint4*)&Opart[(size_t)row * 64 + d8];
  const uint4 c = *(const uint4*)&Opart[(size_t)(row + 65536) * 64 + d8];
  const float inv = 1.f / (Lpart[row] + Lpart[row + 65536]);
  const int bq = ((row >> 15) << 11) | (row & 2047);   // b*2048 + q
  const int h = (row >> 11) & 15;
  uint4 o;
  const uint32_t au[4] = {a.x, a.y, a.z, a.w};
  const uint32_t cu[4] = {c.x, c.y, c.z, c.w};
  uint32_t ou[4];
  #pragma unroll
  for (int k = 0; k < 4; ++k) {
    const float lo = (bflo(au[k]) + bflo(cu[k])) * inv;
    const float hi = (bfhi(au[k]) + bfhi(cu[k])) * inv;
    ou[k] = (uint32_t)f2bf(lo) | ((uint32_t)f2bf(hi) << 16);
  }
  o.x = ou[0]; o.y = ou[1]; o.z = ou[2]; o.w = ou[3];
  *(uint4*)&O[(size_t)bq * 1024 + h * 64 + d8] = o;
}

// ---------- layernorm: LN(X + R + R2), float4-vectorized ----------
__global__ __launch_bounds__(256)
void ln_kernel(const float* __restrict__ X, const float* __restrict__ R,
               const float* __restrict__ R2,
               const float* __restrict__ sc, const float* __restrict__ bi,
               float* __restrict__ outF, unsigned short* __restrict__ outB) {
  const int row = blockIdx.x;
  const int t = threadIdx.x;
  const size_t base = (size_t)row * 1024 + t * 4;
  float4 a  = *(const float4*)&X[base];
  const float4 rv = *(const float4*)&R[base];
  const float4 r2 = *(const float4*)&R2[base];
  a.x += rv.x + r2.x; a.y += rv.y + r2.y; a.z += rv.z + r2.z; a.w += rv.w + r2.w;
  float sum = (a.x + a.y) + (a.z + a.w);
  float sq  = (a.x * a.x + a.y * a.y) + (a.z * a.z + a.w * a.w);
  #pragma unroll
  for (int off = 32; off > 0; off >>= 1) {
    sum += __shfl_down(sum, off);
    sq  += __shfl_down(sq, off);
  }
  __shared__ float s1[4], s2a[4];
  const int wave = t >> 6, lane = t & 63;
  if (lane == 0) { s1[wave] = sum; s2a[wave] = sq; }
  __syncthreads();
  sum = (s1[0] + s1[1]) + (s1[2] + s1[3]);
  sq  = (s2a[0] + s2a[1]) + (s2a[2] + s2a[3]);
  const float mean = sum * (1.f / 1024.f);
  const float var  = sq * (1.f / 1024.f) - mean * mean;
  const float rstd = rsqrtf(var + 1e-5f);
  const float4 s = *(const float4*)&sc[t * 4];
  const float4 bb = *(const float4*)&bi[t * 4];
  float4 y;
  y.x = (a.x - mean) * rstd * s.x + bb.x;
  y.y = (a.y - mean) * rstd * s.y + bb.y;
  y.z = (a.z - mean) * rstd * s.z + bb.z;
  y.w = (a.w - mean) * rstd * s.w + bb.w;
  if (outF) *(float4*)&outF[base] = y;
  if (outB) {
    ushort4 ob; ob.x = f2bf(y.x); ob.y = f2bf(y.y); ob.z = f2bf(y.z); ob.w = f2bf(y.w);
    *(ushort4*)&outB[base] = ob;
  }
}

// ---------- all weight transposes in one launch: fp32 [K,N] -> bf16 [N,K] ----------
__global__ void transpose_all_kernel(const float* __restrict__ Wq, const float* __restrict__ Wk,
                                     const float* __restrict__ Wv, const float* __restrict__ Wo,
                                     const float* __restrict__ W1, const float* __restrict__ W2,
                                     unsigned short* __restrict__ Wqkvt, unsigned short* __restrict__ Wot,
                                     unsigned short* __restrict__ W1t, unsigned short* __restrict__ W2t) {
  const int id = blockIdx.x;   // 12288 tiles of 32x32
  const float* W; unsigned short* Wt; int K, N, tile;
  if (id < 4096) {
    const int w = id >> 10; tile = id & 1023; K = 1024; N = 1024;
    if (w == 0)      { W = Wq; Wt = Wqkvt; }
    else if (w == 1) { W = Wk; Wt = Wqkvt + 1024 * 1024; }
    else if (w == 2) { W = Wv; Wt = Wqkvt + 2048 * 1024; }
    else             { W = Wo; Wt = Wot; }
  } else if (id < 8192) { tile = id - 4096; W = W1; Wt = W1t; K = 1024; N = 4096; }
  else                  { tile = id - 8192; W = W2; Wt = W2t; K = 4096; N = 1024; }
  const int tilesX = N >> 5;
  const int bx = (tile & (tilesX - 1)) * 32;
  const int by = (tile / tilesX) * 32;
  __shared__ float tl[32][33];
  const int tx = threadIdx.x, ty = threadIdx.y;
  #pragma unroll
  for (int i = ty; i < 32; i += 8)
    tl[i][tx] = W[(size_t)(by + i) * N + bx + tx];
  __syncthreads();
  #pragma unroll
  for (int i = ty; i < 32; i += 8)
    Wt[(size_t)(bx + i) * K + by + tx] = f2bf(tl[tx][i]);
}

__global__ void cast_bf16_kernel(const float* __restrict__ in,
                                 unsigned short* __restrict__ out, int n4) {
  const int i = blockIdx.x * 256 + threadIdx.x;
  if (i < n4) {
    float4 v = ((const float4*)in)[i];
    ushort4 o;
    o.x = f2bf(v.x); o.y = f2bf(v.y); o.z = f2bf(v.z); o.w = f2bf(v.w);
    ((ushort4*)out)[i] = o;
  }
}

__global__ void concat3_kernel(const float* __restrict__ a, const float* __restrict__ b,
                               const float* __restrict__ c, float* __restrict__ out) {
  int i = blockIdx.x * 256 + threadIdx.x;
  if (i < 1024) out[i] = a[i];
  else if (i < 2048) out[i] = b[i - 1024];
  else if (i < 3072) out[i] = c[i - 2048];
}

// ---------- launch ----------
extern "C" void kernel_launch(void* const* d_in, const int* in_sizes, int n_in,
                              void* d_out, int out_size, void* d_ws, size_t ws_size,
                              hipStream_t stream) {
  const float* x    = (const float*)d_in[0];
  const float* Wq   = (const float*)d_in[1];
  const float* bq   = (const float*)d_in[2];
  const float* Wk   = (const float*)d_in[3];
  const float* bk   = (const float*)d_in[4];
  const float* Wv   = (const float*)d_in[5];
  const float* bv   = (const float*)d_in[6];
  const float* Wo   = (const float*)d_in[7];
  const float* bo   = (const float*)d_in[8];
  const float* ln1s = (const float*)d_in[9];
  const float* ln1b = (const float*)d_in[10];
  const float* ln2s = (const float*)d_in[11];
  const float* ln2b = (const float*)d_in[12];
  const float* W1   = (const float*)d_in[13];
  const float* b1   = (const float*)d_in[14];
  const float* W2   = (const float*)d_in[15];
  const float* b2   = (const float*)d_in[16];
  float* out = (float*)d_out;

  char* ws = (char*)d_ws;
  const size_t MB = 1u << 20;
  // Lifetime-packed workspace (max 108 MB):
  // [0,32):   QKVb bf16 (24M, dies after attn) -> t1 fp32 x2 (32M) -> ffh bf16 (32M)
  // [32,64):  Vt 32-40, Ob 40-48 (die after O-proj) -> ff fp32 x2 (32M)
  // [48,64):  Opart bf16 x2 (16M, attn->combine); pre-attn: xb 48-56, Wqkvt 56-62
  // [64,80):  x1 fp32
  // [80,80.5): Lpart; [81,83): Wot; [83,91): W1t; [91,99): W2t; [99,~): bqkv; [100,108): x1b
  unsigned short* QKVb = (unsigned short*)(ws + 0);
  float*          t1   = (float*)(ws + 0);
  unsigned short* ffh  = (unsigned short*)(ws + 0);
  unsigned short* Vt   = (unsigned short*)(ws + 32 * MB);
  unsigned short* Ob   = (unsigned short*)(ws + 40 * MB);
  float*          ff   = (float*)(ws + 32 * MB);
  unsigned short* Opart= (unsigned short*)(ws + 48 * MB);
  unsigned short* xb   = (unsigned short*)(ws + 48 * MB);
  unsigned short* Wqkvt= (unsigned short*)(ws + 56 * MB);
  float*          x1   = (float*)(ws + 64 * MB);
  float*          Lpart= (float*)(ws + 80 * MB);
  unsigned short* Wot  = (unsigned short*)(ws + 81 * MB);
  unsigned short* W1t  = (unsigned short*)(ws + 83 * MB);
  unsigned short* W2t  = (unsigned short*)(ws + 91 * MB);
  float*          bqkv = (float*)(ws + 99 * MB);
  unsigned short* x1b  = (unsigned short*)(ws + 100 * MB);

  cast_bf16_kernel<<<4096, 256, 0, stream>>>(x, xb, 1048576);
  transpose_all_kernel<<<12288, dim3(32, 8), 0, stream>>>(Wq, Wk, Wv, Wo, W1, W2,
                                                          Wqkvt, Wot, W1t, W2t);
  concat3_kernel<<<12, 256, 0, stream>>>(bq, bk, bv, bqkv);

  // QKVb = xb @ [Wq|Wk|Wv] + b   (bf16, 4096x3072)
  gemm_bt_kernel<1, 0><<<dim3(24, 32, 1), 256, 0, stream>>>(xb, Wqkvt, QKVb, bqkv, 4096, 3072, 1024, 1024);
  // V transpose (with per-64-tile key permutation)
  repack_v_kernel<<<1024, 256, 0, stream>>>(QKVb, Vt);
  // flash MFMA attention (pipelined), key-split x2 -> unnormalized bf16 partials
  flash_attn_kernel<<<1024, 256, 0, stream>>>(QKVb, Vt, Opart, Lpart);
  // combine -> Ob bf16
  attn_combine_kernel<<<2048, 256, 0, stream>>>(Opart, Lpart, Ob);
  // t1{A,B} = Ob @ Wo + bo (fp32, split-K x2)
  gemm_bt_kernel<0, 0><<<dim3(8, 32, 2), 256, 0, stream>>>(Ob, Wot, t1, bo, 4096, 1024, 1024, 512);
  // x1 = LN(x + t1A + t1B)
  ln_kernel<<<4096, 256, 0, stream>>>(x, t1, t1 + 4096 * 1024, ln1s, ln1b, x1, x1b);
  // ffh = relu(x1b @ W1 + b1) (bf16)
  gemm_bt_kernel<1, 1><<<dim3(32, 32, 1), 256, 0, stream>>>(x1b, W1t, ffh, b1, 4096, 4096, 1024, 1024);
  // ff{A,B} = ffh @ W2 + b2 (fp32, split-K x2)
  gemm_bt_kernel<0, 0><<<dim3(8, 32, 2), 256, 0, stream>>>(ffh, W2t, ff, b2, 4096, 1024, 4096, 2048);
  // out = LN(x1 + ffA + ffB)
  ln_kernel<<<4096, 256, 0, stream>>>(x1, ff, ff + 4096 * 1024, ln2s, ln2b, out, nullptr);

  (void)in_sizes; (void)n_in; (void)out_size; (void)ws_size;
}

// Round 8
// 362.413 us; speedup vs baseline: 1.0089x; 1.0089x over previous
//
#include <hip/hip_runtime.h>
#include <cstdint>

// ---------- types ----------
typedef __bf16 bf16x8 __attribute__((ext_vector_type(8)));
typedef float  floatx4 __attribute__((ext_vector_type(4)));

__device__ __forceinline__ unsigned short f2bf(float x) {
  union { float f; uint32_t u; } v; v.f = x;
  uint32_t r = (v.u + 0x7FFFu + ((v.u >> 16) & 1u)) >> 16;
  return (unsigned short)r;
}
__device__ __forceinline__ float bflo(uint32_t u) {
  union { uint32_t u; float f; } v; v.u = u << 16; return v.f;
}
__device__ __forceinline__ float bfhi(uint32_t u) {
  union { uint32_t u; float f; } v; v.u = u & 0xffff0000u; return v.f;
}
__device__ __forceinline__ float bfu(unsigned short u) {
  union { uint32_t u; float f; } v; v.u = (uint32_t)u << 16; return v.f;
}

// async global->LDS, 16B per lane. LDS dest must be wave-uniform base; HW adds lane*16.
__device__ __forceinline__ void async_copy16(const void* g, void* l) {
  __builtin_amdgcn_global_load_lds(
      (const __attribute__((address_space(1))) uint32_t*)g,
      (__attribute__((address_space(3))) uint32_t*)l, 16, 0, 0);
}

// ---------- bf16 GEMM: C[M,N] = A[M,K] @ Bt[N,K]^T + bias ----------
// 128x128 tile, BK=32, 4 waves 2x2, 4x4 mfma_f32_16x16x32_bf16 per wave.
// PIPELINED K-loop (raw s_barrier + vmcnt(4)); XOR-swizzled LDS; XCD 8x8 block swizzle.
template<int OUT_BF16, int RELU>
__global__ __launch_bounds__(256, 2)
void gemm_bt_kernel(const unsigned short* __restrict__ A,
                    const unsigned short* __restrict__ Bt,
                    void* __restrict__ C, const float* __restrict__ bias,
                    int M, int N, int K, int Kper) {
  __shared__ __align__(16) unsigned short l0A[128 * 32];
  __shared__ __align__(16) unsigned short l0B[128 * 32];
  __shared__ __align__(16) unsigned short l1A[128 * 32];
  __shared__ __align__(16) unsigned short l1B[128 * 32];
  const int tid  = threadIdx.x;
  const int wave = tid >> 6;
  const int lane = tid & 63;

  const int gx = gridDim.x, gy = gridDim.y;
  int flat = blockIdx.y * gx + blockIdx.x;
  const int per = (gx * gy) >> 3;
  flat = (flat & 7) * per + (flat >> 3);
  const int sq = flat >> 6, inner = flat & 63;
  const int sqm = gy >> 3;
  const int m0 = ((sq % sqm) * 8 + (inner & 7)) * 128;
  const int n0 = ((sq / sqm) * 8 + (inner >> 3)) * 128;

  const int kz = blockIdx.z;
  const int wm = (wave >> 1) * 64;
  const int wn = (wave & 1) * 64;
  const int sa_row = lane >> 2;
  const int sa_k   = ((lane & 3) ^ ((lane >> 3) & 3)) * 8;
  const int fr = lane & 15;
  const int fq = lane >> 4;
  const int sw = (fr >> 1) & 3;

  const int r0 = (wave * 2 + 0) * 16 + sa_row;
  const int r1 = (wave * 2 + 1) * 16 + sa_row;
  const unsigned short* A0 = A  + (size_t)(m0 + r0) * K + kz * Kper + sa_k;
  const unsigned short* A1 = A  + (size_t)(m0 + r1) * K + kz * Kper + sa_k;
  const unsigned short* B0 = Bt + (size_t)(n0 + r0) * K + kz * Kper + sa_k;
  const unsigned short* B1 = Bt + (size_t)(n0 + r1) * K + kz * Kper + sa_k;

  floatx4 acc[4][4];
  #pragma unroll
  for (int i = 0; i < 4; ++i)
    #pragma unroll
    for (int j = 0; j < 4; ++j)
      acc[i][j] = (floatx4){0.f, 0.f, 0.f, 0.f};

  const int c0 = (wave * 2 + 0) * 512;
  const int c1 = (wave * 2 + 1) * 512;

#define PREFETCH(kt, LA, LB)                                   \
  do {                                                         \
    const int koff = (kt) << 5;                                \
    async_copy16(A0 + koff, &(LA)[c0]);                        \
    async_copy16(A1 + koff, &(LA)[c1]);                        \
    async_copy16(B0 + koff, &(LB)[c0]);                        \
    async_copy16(B1 + koff, &(LB)[c1]);                        \
  } while (0)

#define COMPUTE(LA, LB)                                                        \
  do {                                                                         \
    bf16x8 af[4], bf[4];                                                       \
    _Pragma("unroll")                                                          \
    for (int t = 0; t < 4; ++t) {                                              \
      af[t] = *(const bf16x8*)&(LA)[(wm + t * 16 + fr) * 32 + (fq ^ sw) * 8];  \
      bf[t] = *(const bf16x8*)&(LB)[(wn + t * 16 + fr) * 32 + (fq ^ sw) * 8];  \
    }                                                                          \
    _Pragma("unroll")                                                          \
    for (int mt = 0; mt < 4; ++mt)                                             \
      _Pragma("unroll")                                                        \
      for (int nt = 0; nt < 4; ++nt)                                           \
        acc[mt][nt] = __builtin_amdgcn_mfma_f32_16x16x32_bf16(af[mt], bf[nt],  \
                                                              acc[mt][nt], 0, 0, 0); \
  } while (0)

  const int kIters = Kper >> 5;   // always even for our shapes
  PREFETCH(0, l0A, l0B);
  for (int kt = 0; kt < kIters; kt += 2) {
    PREFETCH(kt + 1, l1A, l1B);
    asm volatile("s_waitcnt vmcnt(4)" ::: "memory");
    asm volatile("s_barrier" ::: "memory");
    COMPUTE(l0A, l0B);
    asm volatile("s_barrier" ::: "memory");
    if (kt + 2 < kIters) {
      PREFETCH(kt + 2, l0A, l0B);
      asm volatile("s_waitcnt vmcnt(4)" ::: "memory");
    } else {
      asm volatile("s_waitcnt vmcnt(0)" ::: "memory");
    }
    asm volatile("s_barrier" ::: "memory");
    COMPUTE(l1A, l1B);
    asm volatile("s_barrier" ::: "memory");
  }
#undef PREFETCH
#undef COMPUTE

  const float* bp = (kz == 0) ? bias : nullptr;
  char* Cz = (char*)C + (size_t)kz * M * N * (OUT_BF16 ? 2 : 4);
  #pragma unroll
  for (int mt = 0; mt < 4; ++mt) {
    #pragma unroll
    for (int nt = 0; nt < 4; ++nt) {
      const int gn = n0 + wn + nt * 16 + fr;
      const float bv = bp ? bp[gn] : 0.f;
      #pragma unroll
      for (int r = 0; r < 4; ++r) {
        const int gm = m0 + wm + mt * 16 + fq * 4 + r;
        float v = acc[mt][nt][r] + bv;
        if (RELU) v = fmaxf(v, 0.f);
        if (OUT_BF16) ((unsigned short*)Cz)[(size_t)gm * N + gn] = f2bf(v);
        else          ((float*)Cz)[(size_t)gm * N + gn] = v;
      }
    }
  }
}

// ---------- O-proj GEMM with FUSED attention-combine in the A-staging ----------
// A[gm][c] = (Opart0 + Opart1)[row(gm,c)] * invL[row(gm,c)]  where row = (b*16+h)*2048+q.
// M=4096,N=1024,K=1024, split-K 2 (Kper=512). bf16 out. __syncthreads loop (VGPR A-stage).
__global__ __launch_bounds__(256, 2)
void gemm_oproj_kernel(const unsigned short* __restrict__ Opart,
                       const float* __restrict__ invL,
                       const unsigned short* __restrict__ Bt,
                       unsigned short* __restrict__ C,
                       const float* __restrict__ bias) {
  const int K = 1024, N = 1024, M = 4096, Kper = 512;
  __shared__ __align__(16) unsigned short lA[128 * 32];
  __shared__ __align__(16) unsigned short lB[128 * 32];
  const int tid  = threadIdx.x;
  const int wave = tid >> 6;
  const int lane = tid & 63;

  const int gx = gridDim.x, gy = gridDim.y;
  int flat = blockIdx.y * gx + blockIdx.x;
  const int per = (gx * gy) >> 3;
  flat = (flat & 7) * per + (flat >> 3);
  const int sq = flat >> 6, inner = flat & 63;
  const int sqm = gy >> 3;
  const int m0 = ((sq % sqm) * 8 + (inner & 7)) * 128;
  const int n0 = ((sq / sqm) * 8 + (inner >> 3)) * 128;

  const int kz = blockIdx.z;
  const int wm = (wave >> 1) * 64;
  const int wn = (wave & 1) * 64;
  const int sa_row = lane >> 2;
  const int sa_k   = ((lane & 3) ^ ((lane >> 3) & 3)) * 8;
  const int fr = lane & 15;
  const int fq = lane >> 4;
  const int sw = (fr >> 1) & 3;

  const int r0 = (wave * 2 + 0) * 16 + sa_row;
  const int r1 = (wave * 2 + 1) * 16 + sa_row;
  const int gm0 = m0 + r0, gm1 = m0 + r1;
  const int base0 = (gm0 >> 11) * 16 * 2048 + (gm0 & 2047);   // (b*16)*2048 + q
  const int base1 = (gm1 >> 11) * 16 * 2048 + (gm1 & 2047);
  const unsigned short* B0 = Bt + (size_t)(n0 + r0) * K + kz * Kper + sa_k;
  const unsigned short* B1 = Bt + (size_t)(n0 + r1) * K + kz * Kper + sa_k;
  const int c0 = (wave * 2 + 0) * 512;
  const int c1 = (wave * 2 + 1) * 512;

  floatx4 acc[4][4];
  #pragma unroll
  for (int i = 0; i < 4; ++i)
    #pragma unroll
    for (int j = 0; j < 4; ++j)
      acc[i][j] = (floatx4){0.f, 0.f, 0.f, 0.f};

  for (int kt = 0; kt < 16; ++kt) {
    __syncthreads();
    const int kk = kz * Kper + (kt << 5) + sa_k;   // global k index (h*64 + d)
    const int h = kk >> 6, d0 = kk & 63;
    // fused A-stage (normalize two 16B chunks)
    #pragma unroll
    for (int j = 0; j < 2; ++j) {
      const int base = j ? base1 : base0;
      const int cj   = j ? c1 : c0;
      const int rowi = base + h * 2048;
      const size_t idx = (size_t)rowi * 64 + d0;
      const uint4 a = *(const uint4*)(Opart + idx);
      const uint4 b = *(const uint4*)(Opart + idx + 4194304);   // + 65536*64
      const float s = invL[rowi];
      const uint32_t au[4] = {a.x, a.y, a.z, a.w};
      const uint32_t bu[4] = {b.x, b.y, b.z, b.w};
      uint32_t w[4];
      #pragma unroll
      for (int k = 0; k < 4; ++k) {
        const float lo = (bflo(au[k]) + bflo(bu[k])) * s;
        const float hi = (bfhi(au[k]) + bfhi(bu[k])) * s;
        w[k] = (uint32_t)f2bf(lo) | ((uint32_t)f2bf(hi) << 16);
      }
      uint4 wv; wv.x = w[0]; wv.y = w[1]; wv.z = w[2]; wv.w = w[3];
      *(uint4*)&lA[cj + lane * 8] = wv;
    }
    async_copy16(B0 + (kt << 5), &lB[c0]);
    async_copy16(B1 + (kt << 5), &lB[c1]);
    __syncthreads();   // drains vmcnt + lgkmcnt

    bf16x8 af[4], bf[4];
    #pragma unroll
    for (int t = 0; t < 4; ++t) {
      af[t] = *(const bf16x8*)&lA[(wm + t * 16 + fr) * 32 + (fq ^ sw) * 8];
      bf[t] = *(const bf16x8*)&lB[(wn + t * 16 + fr) * 32 + (fq ^ sw) * 8];
    }
    #pragma unroll
    for (int mt = 0; mt < 4; ++mt)
      #pragma unroll
      for (int nt = 0; nt < 4; ++nt)
        acc[mt][nt] = __builtin_amdgcn_mfma_f32_16x16x32_bf16(af[mt], bf[nt], acc[mt][nt], 0, 0, 0);
  }

  const float* bp = (kz == 0) ? bias : nullptr;
  unsigned short* Cz = C + (size_t)kz * M * N;
  #pragma unroll
  for (int mt = 0; mt < 4; ++mt) {
    #pragma unroll
    for (int nt = 0; nt < 4; ++nt) {
      const int gn = n0 + wn + nt * 16 + fr;
      const float bv = bp ? bp[gn] : 0.f;
      #pragma unroll
      for (int r = 0; r < 4; ++r) {
        const int gm = m0 + wm + mt * 16 + fq * 4 + r;
        Cz[(size_t)gm * N + gn] = f2bf(acc[mt][nt][r] + bv);
      }
    }
  }
}

// ---------- repack V: QKVb bf16 [4096,3072] -> Vt [bh][d][s] (keys perm per 64-tile) ----------
__global__ __launch_bounds__(256)
void repack_v_kernel(const unsigned short* __restrict__ X,
                     unsigned short* __restrict__ Vt) {
  const int bid = blockIdx.x;                 // 1024 = b(2) x h(16) x stile(32)
  const int st = bid & 31, h = (bid >> 5) & 15, b = bid >> 9;
  const int bh = b * 16 + h;
  const int s0 = st * 64;
  const int t = threadIdx.x;
  const int sl = t >> 2;
  const int c  = (t & 3) * 16;
  __shared__ __align__(16) unsigned short vt[64][72];
  {
    const uint4* srcV = (const uint4*)(X + (size_t)(b * 2048 + s0 + sl) * 3072 + 2048 + h * 64 + c);
    uint4* dstL = (uint4*)&vt[sl][c];
    dstL[0] = srcV[0]; dstL[1] = srcV[1];
  }
  __syncthreads();
  const int d = t >> 2, cc = (t & 3) * 16;
  unsigned short tmp[16];
  #pragma unroll
  for (int j = 0; j < 16; ++j) {
    const int chat = cc + j;
    const int key = (chat & 3) * 16 + (chat >> 2);   // permutation
    tmp[j] = vt[key][d];
  }
  uint4* dstV = (uint4*)(Vt + ((size_t)bh * 64 + d) * 2048 + s0 + cc);
  dstV[0] = *(uint4*)&tmp[0];
  dstV[1] = *(uint4*)&tmp[8];
}

// ---------- flash attention (MFMA, max-free softmax, key-split x2) ----------
// Single-buffered lK/lV (34.8KB -> 4 blocks/CU). V-fragments hoisted (read once per tile).
// Writes UNNORMALIZED bf16 Opart [ksp][bh*2048+q][64] and fp32 Lpart [ksp][bh*2048+q].
__global__ __launch_bounds__(256, 4)
void flash_attn_kernel(const unsigned short* __restrict__ QKVb,
                       const unsigned short* __restrict__ Vt,
                       unsigned short* __restrict__ Opart, float* __restrict__ Lpart) {
  const int bid = blockIdx.x;               // 1024 = ksp(2) x b(2) x h(16) x qtile(16)
  const int qt = bid & 15, h = (bid >> 4) & 15, b = (bid >> 8) & 1, ksp = bid >> 9;
  const int bh = b * 16 + h;
  const int wave = threadIdx.x >> 6, lane = threadIdx.x & 63;
  const int fr = lane & 15, fq = lane >> 4;

  __shared__ __align__(16) unsigned short lK[64 * 64];      // [key][d] swizzled
  __shared__ __align__(16) unsigned short lV[64 * 64];      // [d][key~perm] swizzled
  __shared__ __align__(16) unsigned short lP[4][32 * 72];   // per-wave [q][key~perm]

  const int q_base = qt * 128 + wave * 32;
  bf16x8 aq[2][2];
  #pragma unroll
  for (int g = 0; g < 2; ++g) {
    const int s2 = q_base + g * 16 + fr;
    const unsigned short* qp = QKVb + (size_t)(b * 2048 + h * 128 + (s2 >> 4)) * 3072
                             + (s2 & 15) * 64 + fq * 8;
    aq[g][0] = *(const bf16x8*)qp;
    aq[g][1] = *(const bf16x8*)(qp + 32);
  }
  floatx4 o_acc[2][4];
  #pragma unroll
  for (int g = 0; g < 2; ++g)
    #pragma unroll
    for (int nt = 0; nt < 4; ++nt) o_acc[g][nt] = (floatx4){0.f, 0.f, 0.f, 0.f};
  float lrow[2][4];
  #pragma unroll
  for (int g = 0; g < 2; ++g)
    #pragma unroll
    for (int r = 0; r < 4; ++r) lrow[g][r] = 0.f;

  const unsigned short* Kg = QKVb + 1024 + h * 64;
  const unsigned short* Vg = Vt + (size_t)bh * 64 * 2048;

  const int srow = lane >> 3;
  const int scol = ((lane & 7) ^ (lane >> 3)) * 8;
  const int sw = fr & 7;
  const int ch0 = wave * 2, ch1 = wave * 2 + 1;
  const int krow0 = ch0 * 8 + srow, krow1 = ch1 * 8 + srow;

  for (int kt = ksp * 16; kt < ksp * 16 + 16; ++kt) {
    __syncthreads();
    async_copy16(Kg + (size_t)(b * 2048 + kt * 64 + krow0) * 3072 + scol, (char*)lK + ch0 * 1024);
    async_copy16(Vg + (size_t)krow0 * 2048 + kt * 64 + scol,              (char*)lV + ch0 * 1024);
    async_copy16(Kg + (size_t)(b * 2048 + kt * 64 + krow1) * 3072 + scol, (char*)lK + ch1 * 1024);
    async_copy16(Vg + (size_t)krow1 * 2048 + kt * 64 + scol,              (char*)lV + ch1 * 1024);
    asm volatile("s_waitcnt vmcnt(0)" ::: "memory");
    __syncthreads();

    // S = Q @ K^T
    floatx4 s_acc[2][4];
    #pragma unroll
    for (int nt = 0; nt < 4; ++nt) {
      const int row = (nt * 16 + fr) * 64;
      bf16x8 bk0 = *(const bf16x8*)&lK[row + ((0 + fq) ^ sw) * 8];
      bf16x8 bk1 = *(const bf16x8*)&lK[row + ((4 + fq) ^ sw) * 8];
      #pragma unroll
      for (int g = 0; g < 2; ++g) {
        floatx4 acc = (floatx4){0.f, 0.f, 0.f, 0.f};
        acc = __builtin_amdgcn_mfma_f32_16x16x32_bf16(aq[g][0], bk0, acc, 0, 0, 0);
        acc = __builtin_amdgcn_mfma_f32_16x16x32_bf16(aq[g][1], bk1, acc, 0, 0, 0);
        s_acc[g][nt] = acc;
      }
    }
    // hoisted V fragments (read once, reused for both g)
    bf16x8 bvv[2][4];
    #pragma unroll
    for (int kk = 0; kk < 2; ++kk)
      #pragma unroll
      for (int nt = 0; nt < 4; ++nt)
        bvv[kk][nt] = *(const bf16x8*)&lV[(nt * 16 + fr) * 64 + ((kk * 4 + fq) ^ sw) * 8];

    // p = exp2(s * 0.125*log2e); packed b64 write: key nt*16+fr -> column fr*4+nt
    #pragma unroll
    for (int g = 0; g < 2; ++g) {
      #pragma unroll
      for (int r = 0; r < 4; ++r) {
        const float p0 = __builtin_amdgcn_exp2f(s_acc[g][0][r] * 0.18033688f);
        const float p1 = __builtin_amdgcn_exp2f(s_acc[g][1][r] * 0.18033688f);
        const float p2 = __builtin_amdgcn_exp2f(s_acc[g][2][r] * 0.18033688f);
        const float p3 = __builtin_amdgcn_exp2f(s_acc[g][3][r] * 0.18033688f);
        lrow[g][r] += (p0 + p1) + (p2 + p3);
        union { float f; uint32_t u; } c0, c1, c2, c3;
        c0.f = p0; c1.f = p1; c2.f = p2; c3.f = p3;
        uint2 pk;
        pk.x = (c1.u & 0xffff0000u) | (c0.u >> 16);
        pk.y = (c3.u & 0xffff0000u) | (c2.u >> 16);
        *(uint2*)&lP[wave][(g * 16 + fq * 4 + r) * 72 + fr * 4] = pk;
      }
    }
    // O += P @ V  (lP wave-private -> lgkmcnt dependency only)
    #pragma unroll
    for (int g = 0; g < 2; ++g) {
      #pragma unroll
      for (int kk = 0; kk < 2; ++kk) {
        bf16x8 ap = *(const bf16x8*)&lP[wave][(g * 16 + fr) * 72 + kk * 32 + fq * 8];
        #pragma unroll
        for (int nt = 0; nt < 4; ++nt)
          o_acc[g][nt] = __builtin_amdgcn_mfma_f32_16x16x32_bf16(ap, bvv[kk][nt], o_acc[g][nt], 0, 0, 0);
      }
    }
  }

  // epilogue: unnormalized bf16 partials + fp32 row sums
  const size_t rbase = (size_t)ksp * 65536 + (size_t)bh * 2048 + q_base;
  #pragma unroll
  for (int g = 0; g < 2; ++g) {
    #pragma unroll
    for (int r = 0; r < 4; ++r) {
      float l = lrow[g][r];
      #pragma unroll
      for (int off = 1; off < 16; off <<= 1) l += __shfl_xor(l, off);
      if (fr == 0) Lpart[rbase + g * 16 + fq * 4 + r] = l;
    }
    #pragma unroll
    for (int nt = 0; nt < 4; ++nt)
      #pragma unroll
      for (int r = 0; r < 4; ++r)
        Opart[(rbase + g * 16 + fq * 4 + r) * 64 + nt * 16 + fr] = f2bf(o_acc[g][nt][r]);
  }
}

// ---------- invL = 1/(L0+L1) ----------
__global__ __launch_bounds__(256)
void invl_kernel(const float* __restrict__ Lpart, float* __restrict__ invL) {
  const int i = blockIdx.x * 256 + threadIdx.x;   // 65536
  invL[i] = 1.f / (Lpart[i] + Lpart[i + 65536]);
}

// ---------- layernorm: LN(X + R + R2); X fp32 or bf16; out fp32 or bf16 ----------
template<int XF32, int OUTF32>
__global__ __launch_bounds__(256)
void ln_kernel(const void* __restrict__ Xv, const unsigned short* __restrict__ R,
               const unsigned short* __restrict__ R2,
               const float* __restrict__ sc, const float* __restrict__ bi,
               float* __restrict__ outF, unsigned short* __restrict__ outB) {
  const int row = blockIdx.x;
  const int t = threadIdx.x;
  const size_t base = (size_t)row * 1024 + t * 4;
  float4 a;
  if (XF32) {
    a = *(const float4*)((const float*)Xv + base);
  } else {
    const ushort4 xu = *(const ushort4*)((const unsigned short*)Xv + base);
    a.x = bfu(xu.x); a.y = bfu(xu.y); a.z = bfu(xu.z); a.w = bfu(xu.w);
  }
  const ushort4 r1u = *(const ushort4*)&R[base];
  const ushort4 r2u = *(const ushort4*)&R2[base];
  a.x += bfu(r1u.x) + bfu(r2u.x);
  a.y += bfu(r1u.y) + bfu(r2u.y);
  a.z += bfu(r1u.z) + bfu(r2u.z);
  a.w += bfu(r1u.w) + bfu(r2u.w);
  float sum = (a.x + a.y) + (a.z + a.w);
  float sq  = (a.x * a.x + a.y * a.y) + (a.z * a.z + a.w * a.w);
  #pragma unroll
  for (int off = 32; off > 0; off >>= 1) {
    sum += __shfl_down(sum, off);
    sq  += __shfl_down(sq, off);
  }
  __shared__ float s1[4], s2a[4];
  const int wave = t >> 6, lane = t & 63;
  if (lane == 0) { s1[wave] = sum; s2a[wave] = sq; }
  __syncthreads();
  sum = (s1[0] + s1[1]) + (s1[2] + s1[3]);
  sq  = (s2a[0] + s2a[1]) + (s2a[2] + s2a[3]);
  const float mean = sum * (1.f / 1024.f);
  const float var  = sq * (1.f / 1024.f) - mean * mean;
  const float rstd = rsqrtf(var + 1e-5f);
  const float4 s = *(const float4*)&sc[t * 4];
  const float4 bb = *(const float4*)&bi[t * 4];
  float4 y;
  y.x = (a.x - mean) * rstd * s.x + bb.x;
  y.y = (a.y - mean) * rstd * s.y + bb.y;
  y.z = (a.z - mean) * rstd * s.z + bb.z;
  y.w = (a.w - mean) * rstd * s.w + bb.w;
  if (OUTF32) {
    *(float4*)&outF[base] = y;
  } else {
    ushort4 ob; ob.x = f2bf(y.x); ob.y = f2bf(y.y); ob.z = f2bf(y.z); ob.w = f2bf(y.w);
    *(ushort4*)&outB[base] = ob;
  }
}

// ---------- prep: weight transposes + x cast + bias concat, ONE launch ----------
__global__ void prep_kernel(const float* __restrict__ Wq, const float* __restrict__ Wk,
                            const float* __restrict__ Wv, const float* __restrict__ Wo,
                            const float* __restrict__ W1, const float* __restrict__ W2,
                            unsigned short* __restrict__ Wqkvt, unsigned short* __restrict__ Wot,
                            unsigned short* __restrict__ W1t, unsigned short* __restrict__ W2t,
                            const float* __restrict__ x, unsigned short* __restrict__ xb,
                            const float* __restrict__ bq, const float* __restrict__ bk,
                            const float* __restrict__ bv, float* __restrict__ bqkv) {
  const int id = blockIdx.x;   // [0,12288) transpose; [12288,16384) cast; [16384,16396) concat
  const int tflat = threadIdx.y * 32 + threadIdx.x;
  if (id >= 16384) {
    const int i = (id - 16384) * 256 + tflat;
    if (i < 1024) bqkv[i] = bq[i];
    else if (i < 2048) bqkv[i] = bk[i - 1024];
    else if (i < 3072) bqkv[i] = bv[i - 2048];
    return;
  }
  if (id >= 12288) {
    const int i = (id - 12288) * 256 + tflat;   // 1048576 float4s
    const float4 v = ((const float4*)x)[i];
    ushort4 o;
    o.x = f2bf(v.x); o.y = f2bf(v.y); o.z = f2bf(v.z); o.w = f2bf(v.w);
    ((ushort4*)xb)[i] = o;
    return;
  }
  const float* W; unsigned short* Wt; int K, N, tile;
  if (id < 4096) {
    const int w = id >> 10; tile = id & 1023; K = 1024; N = 1024;
    if (w == 0)      { W = Wq; Wt = Wqkvt; }
    else if (w == 1) { W = Wk; Wt = Wqkvt + 1024 * 1024; }
    else if (w == 2) { W = Wv; Wt = Wqkvt + 2048 * 1024; }
    else             { W = Wo; Wt = Wot; }
  } else if (id < 8192) { tile = id - 4096; W = W1; Wt = W1t; K = 1024; N = 4096; }
  else                  { tile = id - 8192; W = W2; Wt = W2t; K = 4096; N = 1024; }
  const int tilesX = N >> 5;
  const int bx = (tile & (tilesX - 1)) * 32;
  const int by = (tile / tilesX) * 32;
  __shared__ float tl[32][33];
  const int tx = threadIdx.x, ty = threadIdx.y;
  #pragma unroll
  for (int i = ty; i < 32; i += 8)
    tl[i][tx] = W[(size_t)(by + i) * N + bx + tx];
  __syncthreads();
  #pragma unroll
  for (int i = ty; i < 32; i += 8)
    Wt[(size_t)(bx + i) * K + by + tx] = f2bf(tl[tx][i]);
}

// ---------- launch ----------
extern "C" void kernel_launch(void* const* d_in, const int* in_sizes, int n_in,
                              void* d_out, int out_size, void* d_ws, size_t ws_size,
                              hipStream_t stream) {
  const float* x    = (const float*)d_in[0];
  const float* Wq   = (const float*)d_in[1];
  const float* bq   = (const float*)d_in[2];
  const float* Wk   = (const float*)d_in[3];
  const float* bk   = (const float*)d_in[4];
  const float* Wv   = (const float*)d_in[5];
  const float* bv   = (const float*)d_in[6];
  const float* Wo   = (const float*)d_in[7];
  const float* bo   = (const float*)d_in[8];
  const float* ln1s = (const float*)d_in[9];
  const float* ln1b = (const float*)d_in[10];
  const float* ln2s = (const float*)d_in[11];
  const float* ln2b = (const float*)d_in[12];
  const float* W1   = (const float*)d_in[13];
  const float* b1   = (const float*)d_in[14];
  const float* W2   = (const float*)d_in[15];
  const float* b2   = (const float*)d_in[16];
  float* out = (float*)d_out;

  char* ws = (char*)d_ws;
  const size_t MB = 1u << 20;
  // Workspace (peak ~108 MB):
  // [0,32):   QKVb bf16 (24M, dies after flash) -> t1 bf16 x2 (16M) -> ffh bf16 (32M)
  // [32,48):  Vt 32-40 (dies after flash); ff bf16 x2 (16M, FFN2 out)
  // [48,64):  pre-flash: xb 48-56, Wqkvt 56-62; then Opart bf16 x2 (16M)
  // [80,80.5): Lpart; [80.5,80.75): invL; [81,83): Wot; [83,91): W1t; [91,99): W2t;
  // [99,~): bqkv; [100,108): x1b
  unsigned short* QKVb = (unsigned short*)(ws + 0);
  unsigned short* t1   = (unsigned short*)(ws + 0);
  unsigned short* ffh  = (unsigned short*)(ws + 0);
  unsigned short* Vt   = (unsigned short*)(ws + 32 * MB);
  unsigned short* ff   = (unsigned short*)(ws + 32 * MB);
  unsigned short* xb   = (unsigned short*)(ws + 48 * MB);
  unsigned short* Opart= (unsigned short*)(ws + 48 * MB);
  unsigned short* Wqkvt= (unsigned short*)(ws + 56 * MB);
  float*          Lpart= (float*)(ws + 80 * MB);
  float*          invL = (float*)(ws + 80 * MB + 512 * 1024);
  unsigned short* Wot  = (unsigned short*)(ws + 81 * MB);
  unsigned short* W1t  = (unsigned short*)(ws + 83 * MB);
  unsigned short* W2t  = (unsigned short*)(ws + 91 * MB);
  float*          bqkv = (float*)(ws + 99 * MB);
  unsigned short* x1b  = (unsigned short*)(ws + 100 * MB);

  // prep: 12288 transpose tiles + 4096 cast blocks + 12 concat blocks
  prep_kernel<<<16396, dim3(32, 8), 0, stream>>>(Wq, Wk, Wv, Wo, W1, W2,
                                                 Wqkvt, Wot, W1t, W2t,
                                                 x, xb, bq, bk, bv, bqkv);
  // QKVb = xb @ [Wq|Wk|Wv] + b (bf16, 4096x3072)
  gemm_bt_kernel<1, 0><<<dim3(24, 32, 1), 256, 0, stream>>>(xb, Wqkvt, QKVb, bqkv, 4096, 3072, 1024, 1024);
  // V transpose (with per-64-tile key permutation)
  repack_v_kernel<<<1024, 256, 0, stream>>>(QKVb, Vt);
  // flash MFMA attention, key-split x2 -> unnormalized bf16 partials
  flash_attn_kernel<<<1024, 256, 0, stream>>>(QKVb, Vt, Opart, Lpart);
  // invL = 1/(l0+l1)
  invl_kernel<<<256, 256, 0, stream>>>(Lpart, invL);
  // t1{A,B} = normalize(Opart) @ Wo + bo (bf16, split-K x2, combine fused into A-stage)
  gemm_oproj_kernel<<<dim3(8, 32, 2), 256, 0, stream>>>(Opart, invL, Wot, t1, bo);
  // x1b = LN(x + t1A + t1B)  (bf16 only)
  ln_kernel<1, 0><<<4096, 256, 0, stream>>>(x, t1, t1 + 4096 * 1024, ln1s, ln1b, nullptr, x1b);
  // ffh = relu(x1b @ W1 + b1) (bf16)
  gemm_bt_kernel<1, 1><<<dim3(32, 32, 1), 256, 0, stream>>>(x1b, W1t, ffh, b1, 4096, 4096, 1024, 1024);
  // ff{A,B} = ffh @ W2 + b2 (bf16, split-K x2)
  gemm_bt_kernel<1, 0><<<dim3(8, 32, 2), 256, 0, stream>>>(ffh, W2t, ff, b2, 4096, 1024, 4096, 2048);
  // out = LN(x1b + ffA + ffB)  (fp32)
  ln_kernel<0, 1><<<4096, 256, 0, stream>>>(x1b, ff, ff + 4096 * 1024, ln2s, ln2b, out, nullptr);

  (void)in_sizes; (void)n_in; (void)out_size; (void)ws_size;
}

// Round 9
// 358.511 us; speedup vs baseline: 1.0199x; 1.0109x over previous
//
#include <hip/hip_runtime.h>
#include <cstdint>

// ---------- types ----------
typedef __bf16 bf16x8 __attribute__((ext_vector_type(8)));
typedef float  floatx4 __attribute__((ext_vector_type(4)));

__device__ __forceinline__ unsigned short f2bf(float x) {
  union { float f; uint32_t u; } v; v.f = x;
  uint32_t r = (v.u + 0x7FFFu + ((v.u >> 16) & 1u)) >> 16;
  return (unsigned short)r;
}
__device__ __forceinline__ float bflo(uint32_t u) {
  union { uint32_t u; float f; } v; v.u = u << 16; return v.f;
}
__device__ __forceinline__ float bfhi(uint32_t u) {
  union { uint32_t u; float f; } v; v.u = u & 0xffff0000u; return v.f;
}
__device__ __forceinline__ float bfu(unsigned short u) {
  union { uint32_t u; float f; } v; v.u = (uint32_t)u << 16; return v.f;
}

#define QSCALE 0.18033688011f   // log2(e)/8, folded into Wq/bq at prep

// async global->LDS, 16B per lane. LDS dest must be wave-uniform base; HW adds lane*16.
__device__ __forceinline__ void async_copy16(const void* g, void* l) {
  __builtin_amdgcn_global_load_lds(
      (const __attribute__((address_space(1))) uint32_t*)g,
      (__attribute__((address_space(3))) uint32_t*)l, 16, 0, 0);
}

// ---------- bf16 GEMM: C[M,N] = A[M,K] @ Bt[N,K]^T + bias ----------
// 128x128 tile, BK=32, 4 waves 2x2, 4x4 mfma_f32_16x16x32_bf16 per wave.
// PIPELINED K-loop (raw s_barrier + vmcnt(4)); XOR-swizzled LDS; XCD 8x8 block swizzle.
template<int OUT_BF16, int RELU>
__global__ __launch_bounds__(256, 2)
void gemm_bt_kernel(const unsigned short* __restrict__ A,
                    const unsigned short* __restrict__ Bt,
                    void* __restrict__ C, const float* __restrict__ bias,
                    int M, int N, int K, int Kper) {
  __shared__ __align__(16) unsigned short l0A[128 * 32];
  __shared__ __align__(16) unsigned short l0B[128 * 32];
  __shared__ __align__(16) unsigned short l1A[128 * 32];
  __shared__ __align__(16) unsigned short l1B[128 * 32];
  const int tid  = threadIdx.x;
  const int wave = tid >> 6;
  const int lane = tid & 63;

  const int gx = gridDim.x, gy = gridDim.y;
  int flat = blockIdx.y * gx + blockIdx.x;
  const int per = (gx * gy) >> 3;
  flat = (flat & 7) * per + (flat >> 3);
  const int sq = flat >> 6, inner = flat & 63;
  const int sqm = gy >> 3;
  const int m0 = ((sq % sqm) * 8 + (inner & 7)) * 128;
  const int n0 = ((sq / sqm) * 8 + (inner >> 3)) * 128;

  const int kz = blockIdx.z;
  const int wm = (wave >> 1) * 64;
  const int wn = (wave & 1) * 64;
  const int sa_row = lane >> 2;
  const int sa_k   = ((lane & 3) ^ ((lane >> 3) & 3)) * 8;
  const int fr = lane & 15;
  const int fq = lane >> 4;
  const int sw = (fr >> 1) & 3;

  const int r0 = (wave * 2 + 0) * 16 + sa_row;
  const int r1 = (wave * 2 + 1) * 16 + sa_row;
  const unsigned short* A0 = A  + (size_t)(m0 + r0) * K + kz * Kper + sa_k;
  const unsigned short* A1 = A  + (size_t)(m0 + r1) * K + kz * Kper + sa_k;
  const unsigned short* B0 = Bt + (size_t)(n0 + r0) * K + kz * Kper + sa_k;
  const unsigned short* B1 = Bt + (size_t)(n0 + r1) * K + kz * Kper + sa_k;

  floatx4 acc[4][4];
  #pragma unroll
  for (int i = 0; i < 4; ++i)
    #pragma unroll
    for (int j = 0; j < 4; ++j)
      acc[i][j] = (floatx4){0.f, 0.f, 0.f, 0.f};

  const int c0 = (wave * 2 + 0) * 512;
  const int c1 = (wave * 2 + 1) * 512;

#define PREFETCH(kt, LA, LB)                                   \
  do {                                                         \
    const int koff = (kt) << 5;                                \
    async_copy16(A0 + koff, &(LA)[c0]);                        \
    async_copy16(A1 + koff, &(LA)[c1]);                        \
    async_copy16(B0 + koff, &(LB)[c0]);                        \
    async_copy16(B1 + koff, &(LB)[c1]);                        \
  } while (0)

#define COMPUTE(LA, LB)                                                        \
  do {                                                                         \
    bf16x8 af[4], bf[4];                                                       \
    _Pragma("unroll")                                                          \
    for (int t = 0; t < 4; ++t) {                                              \
      af[t] = *(const bf16x8*)&(LA)[(wm + t * 16 + fr) * 32 + (fq ^ sw) * 8];  \
      bf[t] = *(const bf16x8*)&(LB)[(wn + t * 16 + fr) * 32 + (fq ^ sw) * 8];  \
    }                                                                          \
    _Pragma("unroll")                                                          \
    for (int mt = 0; mt < 4; ++mt)                                             \
      _Pragma("unroll")                                                        \
      for (int nt = 0; nt < 4; ++nt)                                           \
        acc[mt][nt] = __builtin_amdgcn_mfma_f32_16x16x32_bf16(af[mt], bf[nt],  \
                                                              acc[mt][nt], 0, 0, 0); \
  } while (0)

  const int kIters = Kper >> 5;   // always even for our shapes
  PREFETCH(0, l0A, l0B);
  for (int kt = 0; kt < kIters; kt += 2) {
    PREFETCH(kt + 1, l1A, l1B);
    asm volatile("s_waitcnt vmcnt(4)" ::: "memory");
    asm volatile("s_barrier" ::: "memory");
    COMPUTE(l0A, l0B);
    asm volatile("s_barrier" ::: "memory");
    if (kt + 2 < kIters) {
      PREFETCH(kt + 2, l0A, l0B);
      asm volatile("s_waitcnt vmcnt(4)" ::: "memory");
    } else {
      asm volatile("s_waitcnt vmcnt(0)" ::: "memory");
    }
    asm volatile("s_barrier" ::: "memory");
    COMPUTE(l1A, l1B);
    asm volatile("s_barrier" ::: "memory");
  }
#undef PREFETCH
#undef COMPUTE

  const float* bp = (kz == 0) ? bias : nullptr;
  char* Cz = (char*)C + (size_t)kz * M * N * (OUT_BF16 ? 2 : 4);
  #pragma unroll
  for (int mt = 0; mt < 4; ++mt) {
    #pragma unroll
    for (int nt = 0; nt < 4; ++nt) {
      const int gn = n0 + wn + nt * 16 + fr;
      const float bv = bp ? bp[gn] : 0.f;
      #pragma unroll
      for (int r = 0; r < 4; ++r) {
        const int gm = m0 + wm + mt * 16 + fq * 4 + r;
        float v = acc[mt][nt][r] + bv;
        if (RELU) v = fmaxf(v, 0.f);
        if (OUT_BF16) ((unsigned short*)Cz)[(size_t)gm * N + gn] = f2bf(v);
        else          ((float*)Cz)[(size_t)gm * N + gn] = v;
      }
    }
  }
}

// ---------- O-proj GEMM with FUSED attention-combine in the A-staging ----------
// A[gm][c] = (Opart0 + Opart1)[row(gm,c)] * invL[row(gm,c)], row = (b*16+h)*2048+q.
// M=4096,N=1024,K=1024, split-K 4 (Kper=256). bf16 out.
__global__ __launch_bounds__(256, 2)
void gemm_oproj_kernel(const unsigned short* __restrict__ Opart,
                       const float* __restrict__ invL,
                       const unsigned short* __restrict__ Bt,
                       unsigned short* __restrict__ C,
                       const float* __restrict__ bias) {
  const int K = 1024, N = 1024, M = 4096, Kper = 256;
  __shared__ __align__(16) unsigned short lA[128 * 32];
  __shared__ __align__(16) unsigned short lB[128 * 32];
  const int tid  = threadIdx.x;
  const int wave = tid >> 6;
  const int lane = tid & 63;

  const int gx = gridDim.x, gy = gridDim.y;
  int flat = blockIdx.y * gx + blockIdx.x;
  const int per = (gx * gy) >> 3;
  flat = (flat & 7) * per + (flat >> 3);
  const int sq = flat >> 6, inner = flat & 63;
  const int sqm = gy >> 3;
  const int m0 = ((sq % sqm) * 8 + (inner & 7)) * 128;
  const int n0 = ((sq / sqm) * 8 + (inner >> 3)) * 128;

  const int kz = blockIdx.z;
  const int wm = (wave >> 1) * 64;
  const int wn = (wave & 1) * 64;
  const int sa_row = lane >> 2;
  const int sa_k   = ((lane & 3) ^ ((lane >> 3) & 3)) * 8;
  const int fr = lane & 15;
  const int fq = lane >> 4;
  const int sw = (fr >> 1) & 3;

  const int r0 = (wave * 2 + 0) * 16 + sa_row;
  const int r1 = (wave * 2 + 1) * 16 + sa_row;
  const int gm0 = m0 + r0, gm1 = m0 + r1;
  const int base0 = (gm0 >> 11) * 16 * 2048 + (gm0 & 2047);   // (b*16)*2048 + q
  const int base1 = (gm1 >> 11) * 16 * 2048 + (gm1 & 2047);
  const unsigned short* B0 = Bt + (size_t)(n0 + r0) * K + kz * Kper + sa_k;
  const unsigned short* B1 = Bt + (size_t)(n0 + r1) * K + kz * Kper + sa_k;
  const int c0 = (wave * 2 + 0) * 512;
  const int c1 = (wave * 2 + 1) * 512;

  floatx4 acc[4][4];
  #pragma unroll
  for (int i = 0; i < 4; ++i)
    #pragma unroll
    for (int j = 0; j < 4; ++j)
      acc[i][j] = (floatx4){0.f, 0.f, 0.f, 0.f};

  for (int kt = 0; kt < 8; ++kt) {
    __syncthreads();
    const int kk = kz * Kper + (kt << 5) + sa_k;   // global k index (h*64 + d)
    const int h = kk >> 6, d0 = kk & 63;
    #pragma unroll
    for (int j = 0; j < 2; ++j) {
      const int base = j ? base1 : base0;
      const int cj   = j ? c1 : c0;
      const int rowi = base + h * 2048;
      const size_t idx = (size_t)rowi * 64 + d0;
      const uint4 a = *(const uint4*)(Opart + idx);
      const uint4 b = *(const uint4*)(Opart + idx + 4194304);   // + 65536*64
      const float s = invL[rowi];
      const uint32_t au[4] = {a.x, a.y, a.z, a.w};
      const uint32_t bu[4] = {b.x, b.y, b.z, b.w};
      uint32_t w[4];
      #pragma unroll
      for (int k = 0; k < 4; ++k) {
        const float lo = (bflo(au[k]) + bflo(bu[k])) * s;
        const float hi = (bfhi(au[k]) + bfhi(bu[k])) * s;
        w[k] = (uint32_t)f2bf(lo) | ((uint32_t)f2bf(hi) << 16);
      }
      uint4 wv; wv.x = w[0]; wv.y = w[1]; wv.z = w[2]; wv.w = w[3];
      *(uint4*)&lA[cj + lane * 8] = wv;
    }
    async_copy16(B0 + (kt << 5), &lB[c0]);
    async_copy16(B1 + (kt << 5), &lB[c1]);
    __syncthreads();

    bf16x8 af[4], bf[4];
    #pragma unroll
    for (int t = 0; t < 4; ++t) {
      af[t] = *(const bf16x8*)&lA[(wm + t * 16 + fr) * 32 + (fq ^ sw) * 8];
      bf[t] = *(const bf16x8*)&lB[(wn + t * 16 + fr) * 32 + (fq ^ sw) * 8];
    }
    #pragma unroll
    for (int mt = 0; mt < 4; ++mt)
      #pragma unroll
      for (int nt = 0; nt < 4; ++nt)
        acc[mt][nt] = __builtin_amdgcn_mfma_f32_16x16x32_bf16(af[mt], bf[nt], acc[mt][nt], 0, 0, 0);
  }

  const float* bp = (kz == 0) ? bias : nullptr;
  unsigned short* Cz = C + (size_t)kz * M * N;
  #pragma unroll
  for (int mt = 0; mt < 4; ++mt) {
    #pragma unroll
    for (int nt = 0; nt < 4; ++nt) {
      const int gn = n0 + wn + nt * 16 + fr;
      const float bv = bp ? bp[gn] : 0.f;
      #pragma unroll
      for (int r = 0; r < 4; ++r) {
        const int gm = m0 + wm + mt * 16 + fq * 4 + r;
        Cz[(size_t)gm * N + gn] = f2bf(acc[mt][nt][r] + bv);
      }
    }
  }
}

// ---------- repack V: QKVb bf16 [4096,3072] -> Vt [bh][d][s] ----------
// Keys permuted within each 32-tile: position c holds key (c&1)*16 + (c>>1),
// matching flash's packed-P column layout (dot over k is perm-invariant).
__global__ __launch_bounds__(256)
void repack_v_kernel(const unsigned short* __restrict__ X,
                     unsigned short* __restrict__ Vt) {
  const int bid = blockIdx.x;                 // 1024 = b(2) x h(16) x stile(32)
  const int st = bid & 31, h = (bid >> 5) & 15, b = bid >> 9;
  const int bh = b * 16 + h;
  const int s0 = st * 64;
  const int t = threadIdx.x;
  const int sl = t >> 2;
  const int c  = (t & 3) * 16;
  __shared__ __align__(16) unsigned short vt[64][72];
  {
    const uint4* srcV = (const uint4*)(X + (size_t)(b * 2048 + s0 + sl) * 3072 + 2048 + h * 64 + c);
    uint4* dstL = (uint4*)&vt[sl][c];
    dstL[0] = srcV[0]; dstL[1] = srcV[1];
  }
  __syncthreads();
  const int d = t >> 2, cc = (t & 3) * 16;
  unsigned short tmp[16];
  #pragma unroll
  for (int j = 0; j < 16; ++j) {
    const int c64 = cc + j;
    const int grp = c64 >> 5, cw = c64 & 31;
    const int key = grp * 32 + (cw & 1) * 16 + (cw >> 1);   // 32-granular permutation
    tmp[j] = vt[key][d];
  }
  uint4* dstV = (uint4*)(Vt + ((size_t)bh * 64 + d) * 2048 + s0 + cc);
  dstV[0] = *(uint4*)&tmp[0];
  dstV[1] = *(uint4*)&tmp[8];
}

// ---------- flash attention: 32-key HALF-TILE prefetch pipeline ----------
// Block: (ksp, b, h, 128-query tile); 4 waves x 32 q. 32 half-tiles of 32 keys per part.
// LDS 26.6 KB (lK/lV double-buffered at half-tile grain, lP stride 40) -> 4 blocks/CU.
// Raw s_barrier + vmcnt(2): next half's 2 loads/wave issued a full compute-phase ahead.
// Q pre-scaled by log2(e)/8 (folded into Wq/bq) -> p = exp2(s) directly.
// Writes UNNORMALIZED bf16 Opart [ksp][bh*2048+q][64] and fp32 Lpart.
__global__ __launch_bounds__(256, 4)
void flash_attn_kernel(const unsigned short* __restrict__ QKVb,
                       const unsigned short* __restrict__ Vt,
                       unsigned short* __restrict__ Opart, float* __restrict__ Lpart) {
  const int bid = blockIdx.x;               // 1024 = ksp(2) x b(2) x h(16) x qtile(16)
  const int qt = bid & 15, h = (bid >> 4) & 15, b = (bid >> 8) & 1, ksp = bid >> 9;
  const int bh = b * 16 + h;
  const int wave = threadIdx.x >> 6, lane = threadIdx.x & 63;
  const int fr = lane & 15, fq = lane >> 4;

  __shared__ __align__(16) unsigned short lK[2][32 * 64];   // [key][d] swizzled, 2x4KB
  __shared__ __align__(16) unsigned short lV[2][64 * 32];   // [d][key~perm] swizzled, 2x4KB
  __shared__ __align__(16) unsigned short lP[4][32 * 40];   // per-wave [q][key~perm], 10KB

  const int q_base = qt * 128 + wave * 32;
  bf16x8 aq[2][2];
  #pragma unroll
  for (int g = 0; g < 2; ++g) {
    const int s2 = q_base + g * 16 + fr;
    const unsigned short* qp = QKVb + (size_t)(b * 2048 + h * 128 + (s2 >> 4)) * 3072
                             + (s2 & 15) * 64 + fq * 8;
    aq[g][0] = *(const bf16x8*)qp;
    aq[g][1] = *(const bf16x8*)(qp + 32);
  }
  floatx4 o_acc[2][4];
  #pragma unroll
  for (int g = 0; g < 2; ++g)
    #pragma unroll
    for (int nt = 0; nt < 4; ++nt) o_acc[g][nt] = (floatx4){0.f, 0.f, 0.f, 0.f};
  float lrow[2][4];
  #pragma unroll
  for (int g = 0; g < 2; ++g)
    #pragma unroll
    for (int r = 0; r < 4; ++r) lrow[g][r] = 0.f;

  const unsigned short* Kg = QKVb + 1024 + h * 64;
  const unsigned short* Vg = Vt + (size_t)bh * 64 * 2048;

  // staging addresses (per half-tile, +key0 applied in pref)
  const int krow = wave * 8 + (lane >> 3);                    // 0..31
  const int kcol = ((lane & 7) ^ (lane >> 3)) * 8;            // chunk ^ (row&7)
  const unsigned short* Ksrc = Kg + (size_t)(b * 2048 + krow) * 3072 + kcol;
  const int vd   = wave * 16 + (lane >> 2);                   // 0..63
  const int vcol = ((lane & 3) ^ ((lane >> 3) & 3)) * 8;      // chunk ^ ((d>>1)&3)
  const unsigned short* Vsrc = Vg + (size_t)vd * 2048 + vcol;

  auto pref = [&](int key0, int bi) {
    async_copy16(Ksrc + (size_t)key0 * 3072, (char*)lK[bi] + wave * 1024);
    async_copy16(Vsrc + key0,                (char*)lV[bi] + wave * 1024);
  };

  const int swk = fr & 7;
  const int swv = (fr >> 1) & 3;

  auto compute_half = [&](const unsigned short* LK, const unsigned short* LV) {
    // S = Q @ K^T over 32 keys (nt 0..1), k = 64 d
    bf16x8 bk0[2], bk1[2];
    #pragma unroll
    for (int nt = 0; nt < 2; ++nt) {
      const int row = (nt * 16 + fr) * 64;
      bk0[nt] = *(const bf16x8*)&LK[row + ((0 + fq) ^ swk) * 8];
      bk1[nt] = *(const bf16x8*)&LK[row + ((4 + fq) ^ swk) * 8];
    }
    floatx4 s_acc[2][2];
    #pragma unroll
    for (int nt = 0; nt < 2; ++nt)
      #pragma unroll
      for (int g = 0; g < 2; ++g) {
        floatx4 acc = (floatx4){0.f, 0.f, 0.f, 0.f};
        acc = __builtin_amdgcn_mfma_f32_16x16x32_bf16(aq[g][0], bk0[nt], acc, 0, 0, 0);
        acc = __builtin_amdgcn_mfma_f32_16x16x32_bf16(aq[g][1], bk1[nt], acc, 0, 0, 0);
        s_acc[g][nt] = acc;
      }
    // V fragments (B-operand: n = d, k = 32 permuted keys)
    bf16x8 bv[4];
    #pragma unroll
    for (int nt = 0; nt < 4; ++nt) {
      const int d = nt * 16 + fr;
      bv[nt] = *(const bf16x8*)&LV[d * 32 + (fq ^ swv) * 8];
    }
    // p = exp2(s); packed b32 write: keys (0*16+fr, 1*16+fr) -> cols (fr*2, fr*2+1)
    #pragma unroll
    for (int g = 0; g < 2; ++g) {
      #pragma unroll
      for (int r = 0; r < 4; ++r) {
        const float p0 = __builtin_amdgcn_exp2f(s_acc[g][0][r]);
        const float p1 = __builtin_amdgcn_exp2f(s_acc[g][1][r]);
        lrow[g][r] += p0 + p1;
        union { float f; uint32_t u; } z0, z1;
        z0.f = p0; z1.f = p1;
        *(uint32_t*)&lP[wave][(g * 16 + fq * 4 + r) * 40 + fr * 2] =
            (z1.u & 0xffff0000u) | (z0.u >> 16);
      }
    }
    // O += P @ V (k = 32; lP wave-private -> lgkmcnt dependency only)
    #pragma unroll
    for (int g = 0; g < 2; ++g) {
      bf16x8 ap = *(const bf16x8*)&lP[wave][(g * 16 + fr) * 40 + fq * 8];
      #pragma unroll
      for (int nt = 0; nt < 4; ++nt)
        o_acc[g][nt] = __builtin_amdgcn_mfma_f32_16x16x32_bf16(ap, bv[nt], o_acc[g][nt], 0, 0, 0);
    }
  };

  const int key00 = ksp * 1024;
  pref(key00, 0);
  for (int hh = 0; hh < 32; hh += 2) {
    pref(key00 + (hh + 1) * 32, 1);
    asm volatile("s_waitcnt vmcnt(2)" ::: "memory");
    asm volatile("s_barrier" ::: "memory");
    compute_half(lK[0], lV[0]);
    asm volatile("s_barrier" ::: "memory");
    if (hh + 2 < 32) {
      pref(key00 + (hh + 2) * 32, 0);
      asm volatile("s_waitcnt vmcnt(2)" ::: "memory");
    } else {
      asm volatile("s_waitcnt vmcnt(0)" ::: "memory");
    }
    asm volatile("s_barrier" ::: "memory");
    compute_half(lK[1], lV[1]);
    asm volatile("s_barrier" ::: "memory");
  }

  // epilogue: unnormalized bf16 partials + fp32 row sums
  const size_t rbase = (size_t)ksp * 65536 + (size_t)bh * 2048 + q_base;
  #pragma unroll
  for (int g = 0; g < 2; ++g) {
    #pragma unroll
    for (int r = 0; r < 4; ++r) {
      float l = lrow[g][r];
      #pragma unroll
      for (int off = 1; off < 16; off <<= 1) l += __shfl_xor(l, off);
      if (fr == 0) Lpart[rbase + g * 16 + fq * 4 + r] = l;
    }
    #pragma unroll
    for (int nt = 0; nt < 4; ++nt)
      #pragma unroll
      for (int r = 0; r < 4; ++r)
        Opart[(rbase + g * 16 + fq * 4 + r) * 64 + nt * 16 + fr] = f2bf(o_acc[g][nt][r]);
  }
}

// ---------- invL = 1/(L0+L1) ----------
__global__ __launch_bounds__(256)
void invl_kernel(const float* __restrict__ Lpart, float* __restrict__ invL) {
  const int i = blockIdx.x * 256 + threadIdx.x;   // 65536
  invL[i] = 1.f / (Lpart[i] + Lpart[i + 65536]);
}

// ---------- layernorm: LN(X + sum of NPART bf16 partials) ----------
template<int XF32, int OUTF32, int NPART>
__global__ __launch_bounds__(256)
void ln_kernel(const void* __restrict__ Xv, const unsigned short* __restrict__ R,
               const float* __restrict__ sc, const float* __restrict__ bi,
               float* __restrict__ outF, unsigned short* __restrict__ outB) {
  const int row = blockIdx.x;
  const int t = threadIdx.x;
  const size_t base = (size_t)row * 1024 + t * 4;
  float4 a;
  if (XF32) {
    a = *(const float4*)((const float*)Xv + base);
  } else {
    const ushort4 xu = *(const ushort4*)((const unsigned short*)Xv + base);
    a.x = bfu(xu.x); a.y = bfu(xu.y); a.z = bfu(xu.z); a.w = bfu(xu.w);
  }
  #pragma unroll
  for (int p = 0; p < NPART; ++p) {
    const ushort4 ru = *(const ushort4*)&R[(size_t)p * 4194304 + base];
    a.x += bfu(ru.x); a.y += bfu(ru.y); a.z += bfu(ru.z); a.w += bfu(ru.w);
  }
  float sum = (a.x + a.y) + (a.z + a.w);
  float sq  = (a.x * a.x + a.y * a.y) + (a.z * a.z + a.w * a.w);
  #pragma unroll
  for (int off = 32; off > 0; off >>= 1) {
    sum += __shfl_down(sum, off);
    sq  += __shfl_down(sq, off);
  }
  __shared__ float s1[4], s2a[4];
  const int wave = t >> 6, lane = t & 63;
  if (lane == 0) { s1[wave] = sum; s2a[wave] = sq; }
  __syncthreads();
  sum = (s1[0] + s1[1]) + (s1[2] + s1[3]);
  sq  = (s2a[0] + s2a[1]) + (s2a[2] + s2a[3]);
  const float mean = sum * (1.f / 1024.f);
  const float var  = sq * (1.f / 1024.f) - mean * mean;
  const float rstd = rsqrtf(var + 1e-5f);
  const float4 s = *(const float4*)&sc[t * 4];
  const float4 bb = *(const float4*)&bi[t * 4];
  float4 y;
  y.x = (a.x - mean) * rstd * s.x + bb.x;
  y.y = (a.y - mean) * rstd * s.y + bb.y;
  y.z = (a.z - mean) * rstd * s.z + bb.z;
  y.w = (a.w - mean) * rstd * s.w + bb.w;
  if (OUTF32) {
    *(float4*)&outF[base] = y;
  } else {
    ushort4 ob; ob.x = f2bf(y.x); ob.y = f2bf(y.y); ob.z = f2bf(y.z); ob.w = f2bf(y.w);
    *(ushort4*)&outB[base] = ob;
  }
}

// ---------- prep: weight transposes (Wq,bq scaled by log2e/8) + x cast + bias concat ----------
__global__ void prep_kernel(const float* __restrict__ Wq, const float* __restrict__ Wk,
                            const float* __restrict__ Wv, const float* __restrict__ Wo,
                            const float* __restrict__ W1, const float* __restrict__ W2,
                            unsigned short* __restrict__ Wqkvt, unsigned short* __restrict__ Wot,
                            unsigned short* __restrict__ W1t, unsigned short* __restrict__ W2t,
                            const float* __restrict__ x, unsigned short* __restrict__ xb,
                            const float* __restrict__ bq, const float* __restrict__ bk,
                            const float* __restrict__ bv, float* __restrict__ bqkv) {
  const int id = blockIdx.x;   // [0,12288) transpose; [12288,16384) cast; [16384,16396) concat
  const int tflat = threadIdx.y * 32 + threadIdx.x;
  if (id >= 16384) {
    const int i = (id - 16384) * 256 + tflat;
    if (i < 1024) bqkv[i] = bq[i] * QSCALE;
    else if (i < 2048) bqkv[i] = bk[i - 1024];
    else if (i < 3072) bqkv[i] = bv[i - 2048];
    return;
  }
  if (id >= 12288) {
    const int i = (id - 12288) * 256 + tflat;   // 1048576 float4s
    const float4 v = ((const float4*)x)[i];
    ushort4 o;
    o.x = f2bf(v.x); o.y = f2bf(v.y); o.z = f2bf(v.z); o.w = f2bf(v.w);
    ((ushort4*)xb)[i] = o;
    return;
  }
  const float* W; unsigned short* Wt; int K, N, tile;
  float scale = 1.f;
  if (id < 4096) {
    const int w = id >> 10; tile = id & 1023; K = 1024; N = 1024;
    if (w == 0)      { W = Wq; Wt = Wqkvt; scale = QSCALE; }
    else if (w == 1) { W = Wk; Wt = Wqkvt + 1024 * 1024; }
    else if (w == 2) { W = Wv; Wt = Wqkvt + 2048 * 1024; }
    else             { W = Wo; Wt = Wot; }
  } else if (id < 8192) { tile = id - 4096; W = W1; Wt = W1t; K = 1024; N = 4096; }
  else                  { tile = id - 8192; W = W2; Wt = W2t; K = 4096; N = 1024; }
  const int tilesX = N >> 5;
  const int bx = (tile & (tilesX - 1)) * 32;
  const int by = (tile / tilesX) * 32;
  __shared__ float tl[32][33];
  const int tx = threadIdx.x, ty = threadIdx.y;
  #pragma unroll
  for (int i = ty; i < 32; i += 8)
    tl[i][tx] = W[(size_t)(by + i) * N + bx + tx];
  __syncthreads();
  #pragma unroll
  for (int i = ty; i < 32; i += 8)
    Wt[(size_t)(bx + i) * K + by + tx] = f2bf(tl[tx][i] * scale);
}

// ---------- launch ----------
extern "C" void kernel_launch(void* const* d_in, const int* in_sizes, int n_in,
                              void* d_out, int out_size, void* d_ws, size_t ws_size,
                              hipStream_t stream) {
  const float* x    = (const float*)d_in[0];
  const float* Wq   = (const float*)d_in[1];
  const float* bq   = (const float*)d_in[2];
  const float* Wk   = (const float*)d_in[3];
  const float* bk   = (const float*)d_in[4];
  const float* Wv   = (const float*)d_in[5];
  const float* bv   = (const float*)d_in[6];
  const float* Wo   = (const float*)d_in[7];
  const float* bo   = (const float*)d_in[8];
  const float* ln1s = (const float*)d_in[9];
  const float* ln1b = (const float*)d_in[10];
  const float* ln2s = (const float*)d_in[11];
  const float* ln2b = (const float*)d_in[12];
  const float* W1   = (const float*)d_in[13];
  const float* b1   = (const float*)d_in[14];
  const float* W2   = (const float*)d_in[15];
  const float* b2   = (const float*)d_in[16];
  float* out = (float*)d_out;

  char* ws = (char*)d_ws;
  const size_t MB = 1u << 20;
  // Workspace (peak ~108 MB):
  // [0,32):   QKVb bf16 (24M, dies after flash) -> t1 bf16 x4 (32M) -> ffh bf16 (32M)
  // [32,64):  Vt 32-40 (dies after flash) -> ff bf16 x4 (32M)
  // [48,64):  pre-flash: xb 48-56, Wqkvt 56-62; then Opart bf16 x2 (16M, dies after oproj)
  // [80,80.5): Lpart; [80.5,80.75): invL; [81,83): Wot; [83,91): W1t; [91,99): W2t;
  // [99,~): bqkv; [100,108): x1b
  unsigned short* QKVb = (unsigned short*)(ws + 0);
  unsigned short* t1   = (unsigned short*)(ws + 0);
  unsigned short* ffh  = (unsigned short*)(ws + 0);
  unsigned short* Vt   = (unsigned short*)(ws + 32 * MB);
  unsigned short* ff   = (unsigned short*)(ws + 32 * MB);
  unsigned short* xb   = (unsigned short*)(ws + 48 * MB);
  unsigned short* Opart= (unsigned short*)(ws + 48 * MB);
  unsigned short* Wqkvt= (unsigned short*)(ws + 56 * MB);
  float*          Lpart= (float*)(ws + 80 * MB);
  float*          invL = (float*)(ws + 80 * MB + 512 * 1024);
  unsigned short* Wot  = (unsigned short*)(ws + 81 * MB);
  unsigned short* W1t  = (unsigned short*)(ws + 83 * MB);
  unsigned short* W2t  = (unsigned short*)(ws + 91 * MB);
  float*          bqkv = (float*)(ws + 99 * MB);
  unsigned short* x1b  = (unsigned short*)(ws + 100 * MB);

  prep_kernel<<<16396, dim3(32, 8), 0, stream>>>(Wq, Wk, Wv, Wo, W1, W2,
                                                 Wqkvt, Wot, W1t, W2t,
                                                 x, xb, bq, bk, bv, bqkv);
  // QKVb = xb @ [Wq*c|Wk|Wv] + b (bf16, 4096x3072); q-section pre-scaled by log2e/8
  gemm_bt_kernel<1, 0><<<dim3(24, 32, 1), 256, 0, stream>>>(xb, Wqkvt, QKVb, bqkv, 4096, 3072, 1024, 1024);
  // V transpose (32-granular key permutation)
  repack_v_kernel<<<1024, 256, 0, stream>>>(QKVb, Vt);
  // flash MFMA attention (half-tile pipeline), key-split x2 -> unnormalized bf16 partials
  flash_attn_kernel<<<1024, 256, 0, stream>>>(QKVb, Vt, Opart, Lpart);
  // invL = 1/(l0+l1)
  invl_kernel<<<256, 256, 0, stream>>>(Lpart, invL);
  // t1{0..3} = normalize(Opart) @ Wo + bo (bf16, split-K x4, combine fused)
  gemm_oproj_kernel<<<dim3(8, 32, 4), 256, 0, stream>>>(Opart, invL, Wot, t1, bo);
  // x1b = LN(x + sum t1) (bf16)
  ln_kernel<1, 0, 4><<<4096, 256, 0, stream>>>(x, t1, ln1s, ln1b, nullptr, x1b);
  // ffh = relu(x1b @ W1 + b1) (bf16)
  gemm_bt_kernel<1, 1><<<dim3(32, 32, 1), 256, 0, stream>>>(x1b, W1t, ffh, b1, 4096, 4096, 1024, 1024);
  // ff{0..3} = ffh @ W2 + b2 (bf16, split-K x4)
  gemm_bt_kernel<1, 0><<<dim3(8, 32, 4), 256, 0, stream>>>(ffh, W2t, ff, b2, 4096, 1024, 4096, 1024);
  // out = LN(x1b + sum ff) (fp32)
  ln_kernel<0, 1, 4><<<4096, 256, 0, stream>>>(x1b, ff, ln2s, ln2b, out, nullptr);

  (void)in_sizes; (void)n_in; (void)out_size; (void)ws_size;
}